// Round 3
// baseline (1628.091 us; speedup 1.0000x reference)
//
#include <hip/hip_runtime.h>

// QuantumDenseNet R3: (a) all single-mode gate passes fused into the last
// three BS passes of each interferometer half (commuting reorder) ->
// LDS ops -33%, barriers 120->80. (b) complex MAC via packed v_pk_fma_f32
// (float2 ext-vector elementwise fma). (c) strides {1362,227,37,6,1} for
// better LDS bank-pair spread.

typedef float vf2 __attribute__((ext_vector_type(2)));

__device__ __forceinline__ void cmadd(float &ax, float &ay, const float2 u, const float2 v) {
    ax = fmaf(u.x, v.x, ax);
    ax = fmaf(-u.y, v.y, ax);
    ay = fmaf(u.x, v.y, ay);
    ay = fmaf(u.y, v.x, ay);
}

__device__ __forceinline__ void cmaddv(vf2 &acc, const vf2 u, const vf2 v) {
    const vf2 ux = {u.x, u.x};
    const vf2 uy = {-u.y, u.y};
    const vf2 vs = {v.y, v.x};
    acc = __builtin_elementwise_fma(ux, v, acc);
    acc = __builtin_elementwise_fma(uy, vs, acc);
}

// block-diagonal structure of the 36x36 BS gate (total photon number n=0..10)
constexpr int BS_SN[11]  = {1,2,3,4,5,6,5,4,3,2,1};
constexpr int BS_OFF[11] = {0,1,5,14,30,55,91,116,132,141,145};
// padded mode strides (float2 units)
constexpr int MS[5] = {1362, 227, 37, 6, 1};
// apply2 spectator strides (descending) for gate pair (K,K+1)
constexpr int SP2[4][3] = {
    {37, 6, 1},        // K=0: spectators 2,3,4
    {1362, 6, 1},      // K=1: spectators 0,3,4
    {1362, 227, 1},    // K=2: spectators 0,1,4
    {1362, 227, 37},   // K=3: spectators 0,1,2
};

// runtime-indexed copy for gates_kernel packing
__device__ const int d_BS_OFF[12] = {0,1,5,14,30,55,91,116,132,141,145,146};
__device__ const int d_BS_SN[11]  = {1,2,3,4,5,6,5,4,3,2,1};

// ---------------------------------------------------------------------------
// Gate precompute (unchanged from R2): blocks 0..79 -> BS gates packed
// block-diagonal (146 c64), block 80 -> 40 single-mode combined gates.
// ---------------------------------------------------------------------------
__global__ void gates_kernel(const float* __restrict__ lin,
                             const float* __restrict__ act,
                             const float* __restrict__ lact,
                             float2* __restrict__ bs,
                             float2* __restrict__ sg)
{
    __shared__ float2 B0[1296];
    __shared__ float2 B1[1296];
    const int tid = threadIdx.x;

    if (blockIdx.x < 80) {
        const int g = blockIdx.x;
        const int l = g / 20;
        const int w = g % 20;
        const int q = w / 10;
        const int n = w % 10;
        const float theta = lin[l*63 + (q ? 29 : 0) + n];
        const float phi   = lin[l*63 + (q ? 39 : 10) + n];
        const float ts = theta * 0.015625f;
        const float cp = cosf(phi), sp = sinf(phi);
        const float2 u  = make_float2( ts*cp, ts*sp);
        const float2 w2 = make_float2(-ts*cp, ts*sp);

        float2 *R = B0, *T = B1;
        for (int e = tid; e < 1296; e += 256)
            R[e] = make_float2((e % 37 == 0) ? 1.f : 0.f, 0.f);
        __syncthreads();

        for (int k = 16; k >= 1; --k) {
            const float invk = 1.f / (float)k;
            for (int e = tid; e < 1296; e += 256) {
                const int row = e / 36, c = e - row*36;
                const int i = row / 6, j = row - (row/6)*6;
                float ax = 0.f, ay = 0.f;
                if (i < 5 && j > 0) {
                    const float coef = sqrtf((float)((i+1)*j));
                    const float2 x = R[(row+5)*36 + c];
                    const float px = u.x*x.x - u.y*x.y;
                    const float py = u.x*x.y + u.y*x.x;
                    ax = fmaf(coef, px, ax); ay = fmaf(coef, py, ay);
                }
                if (i > 0 && j < 5) {
                    const float coef = sqrtf((float)(i*(j+1)));
                    const float2 x = R[(row-5)*36 + c];
                    const float px = w2.x*x.x - w2.y*x.y;
                    const float py = w2.x*x.y + w2.y*x.x;
                    ax = fmaf(coef, px, ax); ay = fmaf(coef, py, ay);
                }
                T[e] = make_float2(((row == c) ? 1.f : 0.f) + ax*invk, ay*invk);
            }
            __syncthreads();
            float2* tmp = R; R = T; T = tmp;
        }
        for (int s2 = 0; s2 < 6; ++s2) {
            for (int e = tid; e < 1296; e += 256) {
                const int row = e / 36, c = e - row*36;
                float ax = 0.f, ay = 0.f;
                #pragma unroll 6
                for (int k = 0; k < 36; ++k)
                    cmadd(ax, ay, R[row*36 + k], R[k*36 + c]);
                T[e] = make_float2(ax, ay);
            }
            __syncthreads();
            float2* tmp = R; R = T; T = tmp;
        }
        for (int idx = tid; idx < 146; idx += 256) {
            int nn = 0;
            while (idx >= d_BS_OFF[nn+1]) ++nn;
            const int sn  = d_BS_SN[nn];
            const int rel = idx - d_BS_OFF[nn];
            const int p = rel / sn, qq = rel % sn;
            const int imin = (nn > 5) ? (nn - 5) : 0;
            const int row = 5*(imin + p)  + nn;
            const int col = 5*(imin + qq) + nn;
            bs[g*146 + idx] = R[row*36 + col];
        }
    } else {
        const int t = tid;
        if (t >= 40) return;
        const int l  = t / 10;
        const int gi = t % 10;
        if (gi < 5) {
            // Sq[m] = squeeze(r) @ diag(e^{i rphi1 * n})
            const int m = gi;
            const float r    = lin[l*63 + 24 + m];
            const float rphi = (m < 4) ? lin[l*63 + 20 + m] : 0.f;
            float R[36], T[36];
            #pragma unroll
            for (int e = 0; e < 36; ++e) R[e] = (e % 7 == 0) ? 1.f : 0.f;
            float hp[4];
            #pragma unroll
            for (int i = 0; i < 4; ++i)
                hp[i] = 0.5f * r * sqrtf((float)((i+1)*(i+2))) * 0.015625f;
            for (int k = 16; k >= 1; --k) {
                const float invk = 1.f / (float)k;
                #pragma unroll
                for (int i = 0; i < 6; ++i) {
                    #pragma unroll
                    for (int c = 0; c < 6; ++c) {
                        float a = 0.f;
                        if (i < 4)  a = fmaf( hp[i],   R[(i+2)*6 + c], a);
                        if (i >= 2) a = fmaf(-hp[i-2], R[(i-2)*6 + c], a);
                        T[i*6+c] = ((i == c) ? 1.f : 0.f) + a*invk;
                    }
                }
                #pragma unroll
                for (int e = 0; e < 36; ++e) R[e] = T[e];
            }
            for (int s2 = 0; s2 < 6; ++s2) {
                #pragma unroll
                for (int i = 0; i < 6; ++i) {
                    #pragma unroll
                    for (int c = 0; c < 6; ++c) {
                        float a = 0.f;
                        #pragma unroll
                        for (int k = 0; k < 6; ++k) a = fmaf(R[i*6+k], R[k*6+c], a);
                        T[i*6+c] = a;
                    }
                }
                #pragma unroll
                for (int e = 0; e < 36; ++e) R[e] = T[e];
            }
            float2* outp = sg + (l*10 + m)*36;
            #pragma unroll
            for (int c = 0; c < 6; ++c) {
                const float cc = cosf(rphi * (float)c), ss = sinf(rphi * (float)c);
                #pragma unroll
                for (int o = 0; o < 6; ++o)
                    outp[o*6 + c] = make_float2(R[o*6+c]*cc, R[o*6+c]*ss);
            }
        } else {
            // Dp[m] = diag(e^{i kap n^2}) @ disp(dr,dp) @ diag(e^{i rphi2 n})
            const int m = gi - 5;
            const float dr   = lin[l*63 + 53 + m];
            const float dp   = lin[l*63 + 58 + m];
            const float rphi = (m < 4) ? lin[l*63 + 49 + m] : 0.f;
            const float kap  = (l < 3) ? act[l*5 + m] : ((m < 2) ? lact[m] : 0.f);
            const float2 al = make_float2(dr * cosf(dp), dr * sinf(dp));
            float2 R[36], T[36];
            #pragma unroll
            for (int e = 0; e < 36; ++e)
                R[e] = make_float2((e % 7 == 0) ? 1.f : 0.f, 0.f);
            float2 cm[6], cpb[6];
            #pragma unroll
            for (int i = 0; i < 6; ++i) {
                const float sm  = sqrtf((float)i)     * 0.015625f;
                const float sp2 = sqrtf((float)(i+1)) * 0.015625f;
                cm[i]  = make_float2( al.x*sm,  al.y*sm);
                cpb[i] = make_float2(-al.x*sp2, al.y*sp2);
            }
            for (int k = 16; k >= 1; --k) {
                const float invk = 1.f / (float)k;
                #pragma unroll
                for (int i = 0; i < 6; ++i) {
                    #pragma unroll
                    for (int c = 0; c < 6; ++c) {
                        float ax = 0.f, ay = 0.f;
                        if (i >= 1) cmadd(ax, ay, cm[i],  R[(i-1)*6 + c]);
                        if (i < 5)  cmadd(ax, ay, cpb[i], R[(i+1)*6 + c]);
                        T[i*6+c] = make_float2(((i == c) ? 1.f : 0.f) + ax*invk, ay*invk);
                    }
                }
                #pragma unroll
                for (int e = 0; e < 36; ++e) R[e] = T[e];
            }
            for (int s2 = 0; s2 < 6; ++s2) {
                #pragma unroll
                for (int i = 0; i < 6; ++i) {
                    #pragma unroll
                    for (int c = 0; c < 6; ++c) {
                        float ax = 0.f, ay = 0.f;
                        #pragma unroll
                        for (int k = 0; k < 6; ++k) cmadd(ax, ay, R[i*6+k], R[k*6+c]);
                        T[i*6+c] = make_float2(ax, ay);
                    }
                }
                #pragma unroll
                for (int e = 0; e < 36; ++e) R[e] = T[e];
            }
            float2* outp = sg + (l*10 + 5 + m)*36;
            #pragma unroll
            for (int o = 0; o < 6; ++o) {
                const float ko = kap * (float)(o*o);
                const float2 kp = make_float2(cosf(ko), sinf(ko));
                #pragma unroll
                for (int c = 0; c < 6; ++c) {
                    const float rc = rphi * (float)c;
                    const float2 rp = make_float2(cosf(rc), sinf(rc));
                    const float2 z = R[o*6 + c];
                    const float2 t1 = make_float2(kp.x*z.x - kp.y*z.y, kp.x*z.y + kp.y*z.x);
                    outp[o*6 + c] = make_float2(t1.x*rp.x - t1.y*rp.y, t1.x*rp.y + t1.y*rp.x);
                }
            }
        }
    }
}

// ---------------------------------------------------------------------------
// Initial displacement (phi=0 -> real expm): column 0 per (batch, mode).
// ---------------------------------------------------------------------------
__global__ void dcol_kernel(const float* __restrict__ x,
                            float* __restrict__ dcol, const int total)
{
    const int i = blockIdx.x * 256 + threadIdx.x;
    if (i >= total) return;
    const float xv = x[i];
    float a[5];
    #pragma unroll
    for (int j = 0; j < 5; ++j) a[j] = xv * sqrtf((float)(j+1)) * 0.015625f;
    float R[36], T[36];
    #pragma unroll
    for (int e = 0; e < 36; ++e) R[e] = (e % 7 == 0) ? 1.f : 0.f;
    for (int k = 16; k >= 1; --k) {
        const float invk = 1.f / (float)k;
        #pragma unroll
        for (int r = 0; r < 6; ++r) {
            #pragma unroll
            for (int c = 0; c < 6; ++c) {
                float acc = 0.f;
                if (r >= 1) acc = fmaf( a[r-1], R[(r-1)*6 + c], acc);
                if (r < 5)  acc = fmaf(-a[r],   R[(r+1)*6 + c], acc);
                T[r*6+c] = ((r == c) ? 1.f : 0.f) + acc*invk;
            }
        }
        #pragma unroll
        for (int e = 0; e < 36; ++e) R[e] = T[e];
    }
    for (int s2 = 0; s2 < 6; ++s2) {
        #pragma unroll
        for (int r = 0; r < 6; ++r) {
            #pragma unroll
            for (int c = 0; c < 6; ++c) {
                float acc = 0.f;
                #pragma unroll
                for (int k = 0; k < 6; ++k) acc = fmaf(R[r*6+k], R[k*6+c], acc);
                T[r*6+c] = acc;
            }
        }
        #pragma unroll
        for (int e = 0; e < 36; ++e) R[e] = T[e];
    }
    #pragma unroll
    for (int j = 0; j < 6; ++j) dcol[i*6 + j] = R[j*6 + 0];
}

// ---------------------------------------------------------------------------
// Main kernel building blocks
// ---------------------------------------------------------------------------

// BS block-diagonal on register fiber: w = U_bd * v  (v,w indexed a*6+b)
template<int n>
struct BD2 {
    static __device__ __forceinline__ void run(const vf2* __restrict__ U,
                                               const vf2* __restrict__ v,
                                               vf2* __restrict__ w) {
        constexpr int sn = BS_SN[n], uoff = BS_OFF[n];
        constexpr int imin = (n > 5) ? (n - 5) : 0;
        #pragma unroll
        for (int p = 0; p < sn; ++p) {
            vf2 acc = {0.f, 0.f};
            #pragma unroll
            for (int q = 0; q < sn; ++q)
                cmaddv(acc, U[uoff + p*sn + q], v[5*(imin + q) + n]);
            w[5*(imin + p) + n] = acc;
        }
        BD2<n+1>::run(U, v, w);
    }
};
template<>
struct BD2<11> {
    static __device__ __forceinline__ void run(const vf2*, const vf2*, vf2*) {}
};

// dst[a*6+b] = sum_k G[a*6+k] * src[k*6+b]   (gate on row digit)
__device__ __forceinline__ void rowmul(const vf2* __restrict__ G,
                                       const vf2* __restrict__ src, vf2* __restrict__ dst) {
    #pragma unroll
    for (int a = 0; a < 6; ++a)
        #pragma unroll
        for (int b = 0; b < 6; ++b) {
            vf2 acc = {0.f, 0.f};
            #pragma unroll
            for (int k = 0; k < 6; ++k) cmaddv(acc, G[a*6+k], src[k*6+b]);
            dst[a*6+b] = acc;
        }
}
// dst[a*6+b] = sum_k G[b*6+k] * src[a*6+k]   (gate on col digit)
__device__ __forceinline__ void colmul(const vf2* __restrict__ G,
                                       const vf2* __restrict__ src, vf2* __restrict__ dst) {
    #pragma unroll
    for (int a = 0; a < 6; ++a)
        #pragma unroll
        for (int b = 0; b < 6; ++b) {
            vf2 acc = {0.f, 0.f};
            #pragma unroll
            for (int k = 0; k < 6; ++k) cmaddv(acc, G[b*6+k], src[a*6+k]);
            dst[a*6+b] = acc;
        }
}

// One BS pass on mode pair (K,K+1), optionally fused with single-mode gates
// GR (on mode K) and GC (on mode K+1) applied after the BS.
template<int K, bool FR, bool FC>
__device__ __forceinline__ void pass2(const vf2* __restrict__ U,
                                      const vf2* __restrict__ GR,
                                      const vf2* __restrict__ GC,
                                      vf2* __restrict__ psi,
                                      const int base, const bool act)
{
    constexpr int SA = MS[K], SB = MS[K+1];
    vf2 v[36], w[36];
    if (act) {
        #pragma unroll
        for (int a = 0; a < 6; ++a)
            #pragma unroll
            for (int b = 0; b < 6; ++b)
                v[a*6+b] = psi[base + a*SA + b*SB];
    }
    BD2<0>::run(U, v, w);
    if constexpr (FR && FC) {
        rowmul(GR, w, v);
        colmul(GC, v, w);
    } else if constexpr (FC) {
        colmul(GC, w, v);
        #pragma unroll
        for (int e = 0; e < 36; ++e) w[e] = v[e];
    } else if constexpr (FR) {
        rowmul(GR, w, v);
        #pragma unroll
        for (int e = 0; e < 36; ++e) w[e] = v[e];
    }
    if (act) {
        #pragma unroll
        for (int a = 0; a < 6; ++a)
            #pragma unroll
            for (int b = 0; b < 6; ++b)
                psi[base + a*SA + b*SB] = w[a*6+b];
    }
    __syncthreads();
}

__global__ __launch_bounds__(256, 2)
void qnet_kernel(const vf2* __restrict__ bs,
                 const vf2* __restrict__ sg,
                 const float* __restrict__ dcol,
                 float* __restrict__ out)
{
    __shared__ vf2  psi[8166];   // strides {1362,227,37,6,1}, max idx 8165
    __shared__ float aux[32];    // stf (init, 30) then red (epilogue, 8)
    const int tid = threadIdx.x;
    const int b   = blockIdx.x;

    if (tid < 30) aux[tid] = dcol[b*30 + tid];
    __syncthreads();
    for (int e = tid; e < 7776; e += 256) {
        int t = e;
        const int i4 = t % 6; t /= 6;
        const int i3 = t % 6; t /= 6;
        const int i2 = t % 6; t /= 6;
        const int i1 = t % 6; t /= 6;
        const int i0 = t;
        const int addr = i0*1362 + i1*227 + i2*37 + i3*6 + i4;
        const float val = aux[i0]*aux[6+i1]*aux[12+i2]*aux[18+i3]*aux[24+i4];
        psi[addr] = (vf2){val, 0.f};
    }
    __syncthreads();

    // per-thread fiber bases for each K (fixed all kernel)
    const int f  = (tid < 216) ? tid : 215;
    const int d0 = f / 36, rem = f - d0*36;
    const int d1 = rem / 6, d2 = rem - d1*6;
    const bool act = tid < 216;
    int baseK[4];
    #pragma unroll
    for (int k = 0; k < 4; ++k)
        baseK[k] = d0*SP2[k][0] + d1*SP2[k][1] + d2*SP2[k][2];

    for (int l = 0; l < 4; ++l) {
        const vf2* bsl = bs + l * 20 * 146;
        const vf2* sgl = sg + l * 10 * 36;
        for (int half = 0; half < 2; ++half) {
            const vf2* bh = bsl + half * 10 * 146;
            const vf2* sh = sgl + half * 5 * 36;
            // rail order k = {0,2,1,3,0,2,1,3,0,2}; single-mode gates fused
            // into the last pass touching each mode (commuting reorder).
            pass2<0,false,false>(bh + 0*146, nullptr,  nullptr,  psi, baseK[0], act);
            pass2<2,false,false>(bh + 1*146, nullptr,  nullptr,  psi, baseK[2], act);
            pass2<1,false,false>(bh + 2*146, nullptr,  nullptr,  psi, baseK[1], act);
            pass2<3,false,false>(bh + 3*146, nullptr,  nullptr,  psi, baseK[3], act);
            pass2<0,false,false>(bh + 4*146, nullptr,  nullptr,  psi, baseK[0], act);
            pass2<2,false,false>(bh + 5*146, nullptr,  nullptr,  psi, baseK[2], act);
            pass2<1,false,false>(bh + 6*146, nullptr,  nullptr,  psi, baseK[1], act);
            pass2<3,false,true >(bh + 7*146, nullptr,  sh + 4*36, psi, baseK[3], act); // G4 on mode 4
            pass2<0,true ,true >(bh + 8*146, sh + 0*36, sh + 1*36, psi, baseK[0], act); // G0,G1
            pass2<2,true ,true >(bh + 9*146, sh + 2*36, sh + 3*36, psi, baseK[2], act); // G2,G3
        }
    }

    // <psi| X psi> on modes 0,1
    float s0 = 0.f, s1 = 0.f;
    for (int fr = tid; fr < 1296; fr += 256) {
        const int e0 = fr / 216, r0 = fr - e0*216;
        const int e1 = r0 / 36, r1 = r0 - e1*36;
        const int base0 = e0*227 + e1*37 + r1;      // spectators of mode 0
        #pragma unroll
        for (int j = 0; j < 5; ++j) {
            const vf2 p0 = psi[base0 + j*1362];
            const vf2 p1 = psi[base0 + (j+1)*1362];
            s0 = fmaf(sqrtf((float)(j+1)), fmaf(p0.y, p1.y, p0.x*p1.x), s0);
        }
        const int base1 = e0*1362 + e1*37 + r1;     // spectators of mode 1
        #pragma unroll
        for (int j = 0; j < 5; ++j) {
            const vf2 p0 = psi[base1 + j*227];
            const vf2 p1 = psi[base1 + (j+1)*227];
            s1 = fmaf(sqrtf((float)(j+1)), fmaf(p0.y, p1.y, p0.x*p1.x), s1);
        }
    }
    #pragma unroll
    for (int off = 32; off > 0; off >>= 1) {
        s0 += __shfl_down(s0, off, 64);
        s1 += __shfl_down(s1, off, 64);
    }
    if ((tid & 63) == 0) { aux[(tid>>6)*2] = s0; aux[(tid>>6)*2 + 1] = s1; }
    __syncthreads();
    if (tid == 0) {
        out[b*2 + 0] = 2.f*(aux[0] + aux[2] + aux[4] + aux[6]);
        out[b*2 + 1] = 2.f*(aux[1] + aux[3] + aux[5] + aux[7]);
    }
}

// ---------------------------------------------------------------------------
extern "C" void kernel_launch(void* const* d_in, const int* in_sizes, int n_in,
                              void* d_out, int out_size, void* d_ws, size_t ws_size,
                              hipStream_t stream)
{
    const float* x    = (const float*)d_in[0];   // (B, 5)
    const float* lin  = (const float*)d_in[1];   // (4, 63)
    const float* act  = (const float*)d_in[2];   // (3, 5)
    const float* lact = (const float*)d_in[3];   // (5,)
    float* out = (float*)d_out;                  // (B, 2) float32

    const int B = in_sizes[0] / 5;

    // ws layout: 80 packed BS gates (146 c64) | 40 single gates (36 c64) | dcol
    float2* bs = (float2*)d_ws;
    float2* sg = bs + 80*146;
    float*  dc = (float*)(sg + 40*36);

    gates_kernel<<<dim3(81), dim3(256), 0, stream>>>(lin, act, lact, bs, sg);
    const int total = B * 5;
    dcol_kernel<<<dim3((total + 255)/256), dim3(256), 0, stream>>>(x, dc, total);
    qnet_kernel<<<dim3(B), dim3(256), 0, stream>>>((const vf2*)bs, (const vf2*)sg, dc, out);
}

// Round 4
// 1353.843 us; speedup vs baseline: 1.2026x; 1.2026x over previous
//
#include <hip/hip_runtime.h>

// QuantumDenseNet R4: psi stored in LDS as fp16x2 (re,im) -> 31.4 KB/block
// -> 4-5 blocks/CU (16-20 waves, vs 8 at fp32): occupancy was the binding
// constraint (VALUBusy 40%, stalls 60% at 2 waves/SIMD). Structure reverted
// to R2's faster form: incremental block-diagonal BS passes + separate
// apply1 over all 256 threads. Packed fp32 FMA kept. RNE fp16 conversions
// (RTZ would bias the norm down ~3% over 120 stores and fail).

typedef float    vf2 __attribute__((ext_vector_type(2)));
typedef _Float16 h2  __attribute__((ext_vector_type(2)));

__device__ __forceinline__ vf2 h2f(const h2 h) { return (vf2){(float)h.x, (float)h.y}; }
__device__ __forceinline__ h2  f2h(const vf2 v) { return (h2){(_Float16)v.x, (_Float16)v.y}; }

__device__ __forceinline__ void cmadd(float &ax, float &ay, const float2 u, const float2 v) {
    ax = fmaf(u.x, v.x, ax);
    ax = fmaf(-u.y, v.y, ax);
    ay = fmaf(u.x, v.y, ay);
    ay = fmaf(u.y, v.x, ay);
}

__device__ __forceinline__ void cmaddv(vf2 &acc, const vf2 u, const vf2 v) {
    const vf2 ux = {u.x, u.x};
    const vf2 uy = {-u.y, u.y};
    const vf2 vs = {v.y, v.x};
    acc = __builtin_elementwise_fma(ux, v, acc);
    acc = __builtin_elementwise_fma(uy, vs, acc);
}

// block-diagonal structure of the 36x36 BS gate (total photon number n=0..10)
constexpr int BS_SN[11]  = {1,2,3,4,5,6,5,4,3,2,1};
constexpr int BS_OFF[11] = {0,1,5,14,30,55,91,116,132,141,145};
// padded mode strides (h2 = 4B units): banks spread mod 32
constexpr int MS[5] = {1339, 223, 37, 6, 1};
// apply2 spectator strides (descending) for gate pair (K,K+1)
constexpr int SP2[4][3] = {
    {37, 6, 1},        // K=0: spectators 2,3,4
    {1339, 6, 1},      // K=1: spectators 0,3,4
    {1339, 223, 1},    // K=2: spectators 0,1,4
    {1339, 223, 37},   // K=3: spectators 0,1,2
};
// apply1 spectator strides (descending) for mode M
constexpr int SP1[5][4] = {
    {223, 37, 6, 1},
    {1339, 37, 6, 1},
    {1339, 223, 6, 1},
    {1339, 223, 37, 1},
    {1339, 223, 37, 6},
};

// runtime-indexed copy for gates_kernel packing
__device__ const int d_BS_OFF[12] = {0,1,5,14,30,55,91,116,132,141,145,146};
__device__ const int d_BS_SN[11]  = {1,2,3,4,5,6,5,4,3,2,1};

// ---------------------------------------------------------------------------
// Gate precompute (same as R2): blocks 0..79 -> BS gates packed block-diag
// (146 c64), block 80 -> 40 single-mode combined gates (fp32 in ws).
// ---------------------------------------------------------------------------
__global__ void gates_kernel(const float* __restrict__ lin,
                             const float* __restrict__ act,
                             const float* __restrict__ lact,
                             float2* __restrict__ bs,
                             float2* __restrict__ sg)
{
    __shared__ float2 B0[1296];
    __shared__ float2 B1[1296];
    const int tid = threadIdx.x;

    if (blockIdx.x < 80) {
        const int g = blockIdx.x;
        const int l = g / 20;
        const int w = g % 20;
        const int q = w / 10;
        const int n = w % 10;
        const float theta = lin[l*63 + (q ? 29 : 0) + n];
        const float phi   = lin[l*63 + (q ? 39 : 10) + n];
        const float ts = theta * 0.015625f;
        const float cp = cosf(phi), sp = sinf(phi);
        const float2 u  = make_float2( ts*cp, ts*sp);
        const float2 w2 = make_float2(-ts*cp, ts*sp);

        float2 *R = B0, *T = B1;
        for (int e = tid; e < 1296; e += 256)
            R[e] = make_float2((e % 37 == 0) ? 1.f : 0.f, 0.f);
        __syncthreads();

        for (int k = 16; k >= 1; --k) {
            const float invk = 1.f / (float)k;
            for (int e = tid; e < 1296; e += 256) {
                const int row = e / 36, c = e - row*36;
                const int i = row / 6, j = row - (row/6)*6;
                float ax = 0.f, ay = 0.f;
                if (i < 5 && j > 0) {
                    const float coef = sqrtf((float)((i+1)*j));
                    const float2 x = R[(row+5)*36 + c];
                    const float px = u.x*x.x - u.y*x.y;
                    const float py = u.x*x.y + u.y*x.x;
                    ax = fmaf(coef, px, ax); ay = fmaf(coef, py, ay);
                }
                if (i > 0 && j < 5) {
                    const float coef = sqrtf((float)(i*(j+1)));
                    const float2 x = R[(row-5)*36 + c];
                    const float px = w2.x*x.x - w2.y*x.y;
                    const float py = w2.x*x.y + w2.y*x.x;
                    ax = fmaf(coef, px, ax); ay = fmaf(coef, py, ay);
                }
                T[e] = make_float2(((row == c) ? 1.f : 0.f) + ax*invk, ay*invk);
            }
            __syncthreads();
            float2* tmp = R; R = T; T = tmp;
        }
        for (int s2 = 0; s2 < 6; ++s2) {
            for (int e = tid; e < 1296; e += 256) {
                const int row = e / 36, c = e - row*36;
                float ax = 0.f, ay = 0.f;
                #pragma unroll 6
                for (int k = 0; k < 36; ++k)
                    cmadd(ax, ay, R[row*36 + k], R[k*36 + c]);
                T[e] = make_float2(ax, ay);
            }
            __syncthreads();
            float2* tmp = R; R = T; T = tmp;
        }
        for (int idx = tid; idx < 146; idx += 256) {
            int nn = 0;
            while (idx >= d_BS_OFF[nn+1]) ++nn;
            const int sn  = d_BS_SN[nn];
            const int rel = idx - d_BS_OFF[nn];
            const int p = rel / sn, qq = rel % sn;
            const int imin = (nn > 5) ? (nn - 5) : 0;
            const int row = 5*(imin + p)  + nn;
            const int col = 5*(imin + qq) + nn;
            bs[g*146 + idx] = R[row*36 + col];
        }
    } else {
        const int t = tid;
        if (t >= 40) return;
        const int l  = t / 10;
        const int gi = t % 10;
        if (gi < 5) {
            // Sq[m] = squeeze(r) @ diag(e^{i rphi1 * n})
            const int m = gi;
            const float r    = lin[l*63 + 24 + m];
            const float rphi = (m < 4) ? lin[l*63 + 20 + m] : 0.f;
            float R[36], T[36];
            #pragma unroll
            for (int e = 0; e < 36; ++e) R[e] = (e % 7 == 0) ? 1.f : 0.f;
            float hp[4];
            #pragma unroll
            for (int i = 0; i < 4; ++i)
                hp[i] = 0.5f * r * sqrtf((float)((i+1)*(i+2))) * 0.015625f;
            for (int k = 16; k >= 1; --k) {
                const float invk = 1.f / (float)k;
                #pragma unroll
                for (int i = 0; i < 6; ++i) {
                    #pragma unroll
                    for (int c = 0; c < 6; ++c) {
                        float a = 0.f;
                        if (i < 4)  a = fmaf( hp[i],   R[(i+2)*6 + c], a);
                        if (i >= 2) a = fmaf(-hp[i-2], R[(i-2)*6 + c], a);
                        T[i*6+c] = ((i == c) ? 1.f : 0.f) + a*invk;
                    }
                }
                #pragma unroll
                for (int e = 0; e < 36; ++e) R[e] = T[e];
            }
            for (int s2 = 0; s2 < 6; ++s2) {
                #pragma unroll
                for (int i = 0; i < 6; ++i) {
                    #pragma unroll
                    for (int c = 0; c < 6; ++c) {
                        float a = 0.f;
                        #pragma unroll
                        for (int k = 0; k < 6; ++k) a = fmaf(R[i*6+k], R[k*6+c], a);
                        T[i*6+c] = a;
                    }
                }
                #pragma unroll
                for (int e = 0; e < 36; ++e) R[e] = T[e];
            }
            float2* outp = sg + (l*10 + m)*36;
            #pragma unroll
            for (int c = 0; c < 6; ++c) {
                const float cc = cosf(rphi * (float)c), ss = sinf(rphi * (float)c);
                #pragma unroll
                for (int o = 0; o < 6; ++o)
                    outp[o*6 + c] = make_float2(R[o*6+c]*cc, R[o*6+c]*ss);
            }
        } else {
            // Dp[m] = diag(e^{i kap n^2}) @ disp(dr,dp) @ diag(e^{i rphi2 n})
            const int m = gi - 5;
            const float dr   = lin[l*63 + 53 + m];
            const float dp   = lin[l*63 + 58 + m];
            const float rphi = (m < 4) ? lin[l*63 + 49 + m] : 0.f;
            const float kap  = (l < 3) ? act[l*5 + m] : ((m < 2) ? lact[m] : 0.f);
            const float2 al = make_float2(dr * cosf(dp), dr * sinf(dp));
            float2 R[36], T[36];
            #pragma unroll
            for (int e = 0; e < 36; ++e)
                R[e] = make_float2((e % 7 == 0) ? 1.f : 0.f, 0.f);
            float2 cm[6], cpb[6];
            #pragma unroll
            for (int i = 0; i < 6; ++i) {
                const float sm  = sqrtf((float)i)     * 0.015625f;
                const float sp2 = sqrtf((float)(i+1)) * 0.015625f;
                cm[i]  = make_float2( al.x*sm,  al.y*sm);
                cpb[i] = make_float2(-al.x*sp2, al.y*sp2);
            }
            for (int k = 16; k >= 1; --k) {
                const float invk = 1.f / (float)k;
                #pragma unroll
                for (int i = 0; i < 6; ++i) {
                    #pragma unroll
                    for (int c = 0; c < 6; ++c) {
                        float ax = 0.f, ay = 0.f;
                        if (i >= 1) cmadd(ax, ay, cm[i],  R[(i-1)*6 + c]);
                        if (i < 5)  cmadd(ax, ay, cpb[i], R[(i+1)*6 + c]);
                        T[i*6+c] = make_float2(((i == c) ? 1.f : 0.f) + ax*invk, ay*invk);
                    }
                }
                #pragma unroll
                for (int e = 0; e < 36; ++e) R[e] = T[e];
            }
            for (int s2 = 0; s2 < 6; ++s2) {
                #pragma unroll
                for (int i = 0; i < 6; ++i) {
                    #pragma unroll
                    for (int c = 0; c < 6; ++c) {
                        float ax = 0.f, ay = 0.f;
                        #pragma unroll
                        for (int k = 0; k < 6; ++k) cmadd(ax, ay, R[i*6+k], R[k*6+c]);
                        T[i*6+c] = make_float2(ax, ay);
                    }
                }
                #pragma unroll
                for (int e = 0; e < 36; ++e) R[e] = T[e];
            }
            float2* outp = sg + (l*10 + 5 + m)*36;
            #pragma unroll
            for (int o = 0; o < 6; ++o) {
                const float ko = kap * (float)(o*o);
                const float2 kp = make_float2(cosf(ko), sinf(ko));
                #pragma unroll
                for (int c = 0; c < 6; ++c) {
                    const float rc = rphi * (float)c;
                    const float2 rp = make_float2(cosf(rc), sinf(rc));
                    const float2 z = R[o*6 + c];
                    const float2 t1 = make_float2(kp.x*z.x - kp.y*z.y, kp.x*z.y + kp.y*z.x);
                    outp[o*6 + c] = make_float2(t1.x*rp.x - t1.y*rp.y, t1.x*rp.y + t1.y*rp.x);
                }
            }
        }
    }
}

// ---------------------------------------------------------------------------
// Initial displacement (phi=0 -> real expm): column 0 per (batch, mode).
// ---------------------------------------------------------------------------
__global__ void dcol_kernel(const float* __restrict__ x,
                            float* __restrict__ dcol, const int total)
{
    const int i = blockIdx.x * 256 + threadIdx.x;
    if (i >= total) return;
    const float xv = x[i];
    float a[5];
    #pragma unroll
    for (int j = 0; j < 5; ++j) a[j] = xv * sqrtf((float)(j+1)) * 0.015625f;
    float R[36], T[36];
    #pragma unroll
    for (int e = 0; e < 36; ++e) R[e] = (e % 7 == 0) ? 1.f : 0.f;
    for (int k = 16; k >= 1; --k) {
        const float invk = 1.f / (float)k;
        #pragma unroll
        for (int r = 0; r < 6; ++r) {
            #pragma unroll
            for (int c = 0; c < 6; ++c) {
                float acc = 0.f;
                if (r >= 1) acc = fmaf( a[r-1], R[(r-1)*6 + c], acc);
                if (r < 5)  acc = fmaf(-a[r],   R[(r+1)*6 + c], acc);
                T[r*6+c] = ((r == c) ? 1.f : 0.f) + acc*invk;
            }
        }
        #pragma unroll
        for (int e = 0; e < 36; ++e) R[e] = T[e];
    }
    for (int s2 = 0; s2 < 6; ++s2) {
        #pragma unroll
        for (int r = 0; r < 6; ++r) {
            #pragma unroll
            for (int c = 0; c < 6; ++c) {
                float acc = 0.f;
                #pragma unroll
                for (int k = 0; k < 6; ++k) acc = fmaf(R[r*6+k], R[k*6+c], acc);
                T[r*6+c] = acc;
            }
        }
        #pragma unroll
        for (int e = 0; e < 36; ++e) R[e] = T[e];
    }
    #pragma unroll
    for (int j = 0; j < 6; ++j) dcol[i*6 + j] = R[j*6 + 0];
}

// ---------------------------------------------------------------------------
// Main kernel building blocks (fp16x2 psi in LDS)
// ---------------------------------------------------------------------------

// Incremental block-diagonal apply2 (R2 structure): per n-block read sn,
// compute sn^2 cMAC, write sn. Blocks are disjoint -> in-place safe, and
// independent -> compiler overlaps block n+1 loads with block n compute.
template<int K, int n>
struct BDBlock {
    static __device__ __forceinline__ void run(const vf2* __restrict__ U,
                                               h2* __restrict__ psi,
                                               const int base, const bool act) {
        constexpr int SA = MS[K], SB = MS[K+1];
        constexpr int sn = BS_SN[n], uoff = BS_OFF[n];
        constexpr int imin = (n > 5) ? (n - 5) : 0;
        vf2 vb[sn];
        #pragma unroll
        for (int q = 0; q < sn; ++q) {
            const int c = 5*(imin + q) + n;
            vb[q] = h2f(psi[base + (c/6)*SA + (c%6)*SB]);
        }
        vf2 ob[sn];
        #pragma unroll
        for (int p = 0; p < sn; ++p) {
            vf2 acc = {0.f, 0.f};
            #pragma unroll
            for (int q = 0; q < sn; ++q)
                cmaddv(acc, U[uoff + p*sn + q], vb[q]);
            ob[p] = acc;
        }
        if (act) {
            #pragma unroll
            for (int p = 0; p < sn; ++p) {
                const int c = 5*(imin + p) + n;
                psi[base + (c/6)*SA + (c%6)*SB] = f2h(ob[p]);
            }
        }
        BDBlock<K, n+1>::run(U, psi, base, act);
    }
};
template<int K>
struct BDBlock<K, 11> {
    static __device__ __forceinline__ void run(const vf2*, h2*, int, bool) {}
};

template<int K>
__device__ __forceinline__ void apply2_bd(const vf2* __restrict__ U,
                                          h2* __restrict__ psi,
                                          const int base, const bool act)
{
    BDBlock<K, 0>::run(U, psi, base, act);
    __syncthreads();
}

template<int M5>
__device__ __forceinline__ void apply1_u(const vf2* __restrict__ G,
                                         h2* __restrict__ psi, const int tid)
{
    constexpr int SM = MS[M5];
    vf2 g[36];
    #pragma unroll
    for (int k = 0; k < 36; ++k) g[k] = G[k];   // block-uniform -> scalar loads
    for (int it = 0; it < 6; ++it) {
        const int fr = tid + it*256;
        const bool act = fr < 1296;
        const int f  = act ? fr : 1295;
        const int d0 = f / 216, r0 = f - d0*216;
        const int d1 = r0 / 36, r1 = r0 - d1*36;
        const int d2 = r1 / 6,  d3 = r1 - d2*6;
        const int base = d0*SP1[M5][0] + d1*SP1[M5][1] + d2*SP1[M5][2] + d3*SP1[M5][3];
        vf2 v6[6];
        #pragma unroll
        for (int j = 0; j < 6; ++j) v6[j] = h2f(psi[base + j*SM]);
        vf2 o6[6];
        #pragma unroll
        for (int o = 0; o < 6; ++o) {
            vf2 acc = {0.f, 0.f};
            #pragma unroll
            for (int j = 0; j < 6; ++j) cmaddv(acc, g[o*6 + j], v6[j]);
            o6[o] = acc;
        }
        if (act) {
            #pragma unroll
            for (int o = 0; o < 6; ++o) psi[base + o*SM] = f2h(o6[o]);
        }
    }
    __syncthreads();
}

__global__ __launch_bounds__(256, 4)
void qnet_kernel(const vf2* __restrict__ bs,
                 const vf2* __restrict__ sg,
                 const float* __restrict__ dcol,
                 float* __restrict__ out)
{
    __shared__ h2    psi[8034];   // strides {1339,223,37,6,1}; 32136 B
    __shared__ float aux[32];     // stf (init, 30) then red (epilogue, 8)
    const int tid = threadIdx.x;
    const int b   = blockIdx.x;

    if (tid < 30) aux[tid] = dcol[b*30 + tid];
    __syncthreads();
    for (int e = tid; e < 7776; e += 256) {
        int t = e;
        const int i4 = t % 6; t /= 6;
        const int i3 = t % 6; t /= 6;
        const int i2 = t % 6; t /= 6;
        const int i1 = t % 6; t /= 6;
        const int i0 = t;
        const int addr = i0*1339 + i1*223 + i2*37 + i3*6 + i4;
        const float val = aux[i0]*aux[6+i1]*aux[12+i2]*aux[18+i3]*aux[24+i4];
        psi[addr] = f2h((vf2){val, 0.f});
    }
    __syncthreads();

    // per-thread fiber bases for each K (fixed all kernel)
    const int f  = (tid < 216) ? tid : 215;
    const int d0 = f / 36, rem = f - d0*36;
    const int d1 = rem / 6, d2 = rem - d1*6;
    const bool act = tid < 216;
    int baseK[4];
    #pragma unroll
    for (int k = 0; k < 4; ++k)
        baseK[k] = d0*SP2[k][0] + d1*SP2[k][1] + d2*SP2[k][2];

    for (int l = 0; l < 4; ++l) {
        const vf2* bsl = bs + l * 20 * 146;
        const vf2* sgl = sg + l * 10 * 36;
        for (int half = 0; half < 2; ++half) {
            const vf2* bh = bsl + half * 10 * 146;
            // rail order k = {0,2,1,3,0,2,1,3,0,2}
            apply2_bd<0>(bh + 0*146, psi, baseK[0], act);
            apply2_bd<2>(bh + 1*146, psi, baseK[2], act);
            apply2_bd<1>(bh + 2*146, psi, baseK[1], act);
            apply2_bd<3>(bh + 3*146, psi, baseK[3], act);
            apply2_bd<0>(bh + 4*146, psi, baseK[0], act);
            apply2_bd<2>(bh + 5*146, psi, baseK[2], act);
            apply2_bd<1>(bh + 6*146, psi, baseK[1], act);
            apply2_bd<3>(bh + 7*146, psi, baseK[3], act);
            apply2_bd<0>(bh + 8*146, psi, baseK[0], act);
            apply2_bd<2>(bh + 9*146, psi, baseK[2], act);
            const vf2* sh = sgl + half * 5 * 36;
            apply1_u<0>(sh + 0*36, psi, tid);
            apply1_u<1>(sh + 1*36, psi, tid);
            apply1_u<2>(sh + 2*36, psi, tid);
            apply1_u<3>(sh + 3*36, psi, tid);
            apply1_u<4>(sh + 4*36, psi, tid);
        }
    }

    // <psi| X psi> on modes 0,1
    float s0 = 0.f, s1 = 0.f;
    for (int fr = tid; fr < 1296; fr += 256) {
        const int e0 = fr / 216, r0 = fr - e0*216;
        const int e1 = r0 / 36, r1 = r0 - e1*36;
        const int base0 = e0*223 + e1*37 + r1;      // spectators of mode 0
        #pragma unroll
        for (int j = 0; j < 5; ++j) {
            const vf2 p0 = h2f(psi[base0 + j*1339]);
            const vf2 p1 = h2f(psi[base0 + (j+1)*1339]);
            s0 = fmaf(sqrtf((float)(j+1)), fmaf(p0.y, p1.y, p0.x*p1.x), s0);
        }
        const int base1 = e0*1339 + e1*37 + r1;     // spectators of mode 1
        #pragma unroll
        for (int j = 0; j < 5; ++j) {
            const vf2 p0 = h2f(psi[base1 + j*223]);
            const vf2 p1 = h2f(psi[base1 + (j+1)*223]);
            s1 = fmaf(sqrtf((float)(j+1)), fmaf(p0.y, p1.y, p0.x*p1.x), s1);
        }
    }
    #pragma unroll
    for (int off = 32; off > 0; off >>= 1) {
        s0 += __shfl_down(s0, off, 64);
        s1 += __shfl_down(s1, off, 64);
    }
    if ((tid & 63) == 0) { aux[(tid>>6)*2] = s0; aux[(tid>>6)*2 + 1] = s1; }
    __syncthreads();
    if (tid == 0) {
        out[b*2 + 0] = 2.f*(aux[0] + aux[2] + aux[4] + aux[6]);
        out[b*2 + 1] = 2.f*(aux[1] + aux[3] + aux[5] + aux[7]);
    }
}

// ---------------------------------------------------------------------------
extern "C" void kernel_launch(void* const* d_in, const int* in_sizes, int n_in,
                              void* d_out, int out_size, void* d_ws, size_t ws_size,
                              hipStream_t stream)
{
    const float* x    = (const float*)d_in[0];   // (B, 5)
    const float* lin  = (const float*)d_in[1];   // (4, 63)
    const float* act  = (const float*)d_in[2];   // (3, 5)
    const float* lact = (const float*)d_in[3];   // (5,)
    float* out = (float*)d_out;                  // (B, 2) float32

    const int B = in_sizes[0] / 5;

    // ws layout: 80 packed BS gates (146 c64) | 40 single gates (36 c64) | dcol
    float2* bs = (float2*)d_ws;
    float2* sg = bs + 80*146;
    float*  dc = (float*)(sg + 40*36);

    gates_kernel<<<dim3(81), dim3(256), 0, stream>>>(lin, act, lact, bs, sg);
    const int total = B * 5;
    dcol_kernel<<<dim3((total + 255)/256), dim3(256), 0, stream>>>(x, dc, total);
    qnet_kernel<<<dim3(B), dim3(256), 0, stream>>>((const vf2*)bs, (const vf2*)sg, dc, out);
}

// Round 5
// 1050.809 us; speedup vs baseline: 1.5494x; 1.2884x over previous
//
#include <hip/hip_runtime.h>

// QuantumDenseNet R5: (a) complex MAC via v_dot2_f32_f16 (fdot2): gates
// pre-packed as h2 pairs (re,-im),(im,re); psi h2 feeds dot2 directly ->
// no load-side cvt, fp32 accumulation. (b) strides {1365,227,37,6,1}
// (mod32 {21,3,5,6,1}) -> <=2-4-way LDS conflicts in every pass. (c) psi
// = 8190 h2 = 32760 B; stf/red live in the layout's padding gaps ->
// exactly 5 blocks/CU (160 KiB LDS).

typedef float    vf2 __attribute__((ext_vector_type(2)));
typedef _Float16 h2  __attribute__((ext_vector_type(2)));

__device__ __forceinline__ float fdot2(const h2 a, const h2 b, const float c) {
    return __builtin_amdgcn_fdot2(a, b, c, false);
}
__device__ __forceinline__ vf2 h2f(const h2 h) { return (vf2){(float)h.x, (float)h.y}; }

__device__ __forceinline__ void cmadd(float &ax, float &ay, const float2 u, const float2 v) {
    ax = fmaf(u.x, v.x, ax);
    ax = fmaf(-u.y, v.y, ax);
    ay = fmaf(u.x, v.y, ay);
    ay = fmaf(u.y, v.x, ay);
}

// block-diagonal structure of the 36x36 BS gate (total photon number n=0..10)
constexpr int BS_SN[11]  = {1,2,3,4,5,6,5,4,3,2,1};
constexpr int BS_OFF[11] = {0,1,5,14,30,55,91,116,132,141,145};
// mode strides (h2 = 4B units); mod 32 = {21,3,5,6,1}
constexpr int MS[5] = {1365, 227, 37, 6, 1};
// apply2 spectator strides (descending) for gate pair (K,K+1)
constexpr int SP2[4][3] = {
    {37, 6, 1},        // K=0: spectators 2,3,4
    {1365, 6, 1},      // K=1: spectators 0,3,4
    {1365, 227, 1},    // K=2: spectators 0,1,4
    {1365, 227, 37},   // K=3: spectators 0,1,2
};
// apply1 spectator strides (descending) for mode M
constexpr int SP1[5][4] = {
    {227, 37, 6, 1},
    {1365, 37, 6, 1},
    {1365, 227, 6, 1},
    {1365, 227, 37, 1},
    {1365, 227, 37, 6},
};

// runtime-indexed copy for gates_kernel packing
__device__ const int d_BS_OFF[12] = {0,1,5,14,30,55,91,116,132,141,145,146};
__device__ const int d_BS_SN[11]  = {1,2,3,4,5,6,5,4,3,2,1};

// ---------------------------------------------------------------------------
// Gate precompute: blocks 0..79 -> BS gates (fp32 expm in LDS, packed
// block-diag as h2 dot2-pairs: 292 h2/gate), block 80 -> 40 single-mode
// combined gates (72 h2/gate).
// ---------------------------------------------------------------------------
__global__ void gates_kernel(const float* __restrict__ lin,
                             const float* __restrict__ act,
                             const float* __restrict__ lact,
                             h2* __restrict__ bsh,
                             h2* __restrict__ sgh)
{
    __shared__ float2 B0[1296];
    __shared__ float2 B1[1296];
    const int tid = threadIdx.x;

    if (blockIdx.x < 80) {
        const int g = blockIdx.x;
        const int l = g / 20;
        const int w = g % 20;
        const int q = w / 10;
        const int n = w % 10;
        const float theta = lin[l*63 + (q ? 29 : 0) + n];
        const float phi   = lin[l*63 + (q ? 39 : 10) + n];
        const float ts = theta * 0.015625f;
        const float cp = cosf(phi), sp = sinf(phi);
        const float2 u  = make_float2( ts*cp, ts*sp);
        const float2 w2 = make_float2(-ts*cp, ts*sp);

        float2 *R = B0, *T = B1;
        for (int e = tid; e < 1296; e += 256)
            R[e] = make_float2((e % 37 == 0) ? 1.f : 0.f, 0.f);
        __syncthreads();

        for (int k = 16; k >= 1; --k) {
            const float invk = 1.f / (float)k;
            for (int e = tid; e < 1296; e += 256) {
                const int row = e / 36, c = e - row*36;
                const int i = row / 6, j = row - (row/6)*6;
                float ax = 0.f, ay = 0.f;
                if (i < 5 && j > 0) {
                    const float coef = sqrtf((float)((i+1)*j));
                    const float2 x = R[(row+5)*36 + c];
                    const float px = u.x*x.x - u.y*x.y;
                    const float py = u.x*x.y + u.y*x.x;
                    ax = fmaf(coef, px, ax); ay = fmaf(coef, py, ay);
                }
                if (i > 0 && j < 5) {
                    const float coef = sqrtf((float)(i*(j+1)));
                    const float2 x = R[(row-5)*36 + c];
                    const float px = w2.x*x.x - w2.y*x.y;
                    const float py = w2.x*x.y + w2.y*x.x;
                    ax = fmaf(coef, px, ax); ay = fmaf(coef, py, ay);
                }
                T[e] = make_float2(((row == c) ? 1.f : 0.f) + ax*invk, ay*invk);
            }
            __syncthreads();
            float2* tmp = R; R = T; T = tmp;
        }
        for (int s2 = 0; s2 < 6; ++s2) {
            for (int e = tid; e < 1296; e += 256) {
                const int row = e / 36, c = e - row*36;
                float ax = 0.f, ay = 0.f;
                #pragma unroll 6
                for (int k = 0; k < 36; ++k)
                    cmadd(ax, ay, R[row*36 + k], R[k*36 + c]);
                T[e] = make_float2(ax, ay);
            }
            __syncthreads();
            float2* tmp = R; R = T; T = tmp;
        }
        for (int idx = tid; idx < 146; idx += 256) {
            int nn = 0;
            while (idx >= d_BS_OFF[nn+1]) ++nn;
            const int sn  = d_BS_SN[nn];
            const int rel = idx - d_BS_OFF[nn];
            const int p = rel / sn, qq = rel % sn;
            const int imin = (nn > 5) ? (nn - 5) : 0;
            const int row = 5*(imin + p)  + nn;
            const int col = 5*(imin + qq) + nn;
            const float2 z = R[row*36 + col];
            bsh[g*292 + 2*idx    ] = (h2){(_Float16)z.x, (_Float16)(-z.y)};
            bsh[g*292 + 2*idx + 1] = (h2){(_Float16)z.y, (_Float16)( z.x)};
        }
    } else {
        const int t = tid;
        if (t >= 40) return;
        const int l  = t / 10;
        const int gi = t % 10;
        float2 G[36];
        if (gi < 5) {
            // Sq[m] = squeeze(r) @ diag(e^{i rphi1 * n})
            const int m = gi;
            const float r    = lin[l*63 + 24 + m];
            const float rphi = (m < 4) ? lin[l*63 + 20 + m] : 0.f;
            float R[36], T[36];
            #pragma unroll
            for (int e = 0; e < 36; ++e) R[e] = (e % 7 == 0) ? 1.f : 0.f;
            float hp[4];
            #pragma unroll
            for (int i = 0; i < 4; ++i)
                hp[i] = 0.5f * r * sqrtf((float)((i+1)*(i+2))) * 0.015625f;
            for (int k = 16; k >= 1; --k) {
                const float invk = 1.f / (float)k;
                #pragma unroll
                for (int i = 0; i < 6; ++i) {
                    #pragma unroll
                    for (int c = 0; c < 6; ++c) {
                        float a = 0.f;
                        if (i < 4)  a = fmaf( hp[i],   R[(i+2)*6 + c], a);
                        if (i >= 2) a = fmaf(-hp[i-2], R[(i-2)*6 + c], a);
                        T[i*6+c] = ((i == c) ? 1.f : 0.f) + a*invk;
                    }
                }
                #pragma unroll
                for (int e = 0; e < 36; ++e) R[e] = T[e];
            }
            for (int s2 = 0; s2 < 6; ++s2) {
                #pragma unroll
                for (int i = 0; i < 6; ++i) {
                    #pragma unroll
                    for (int c = 0; c < 6; ++c) {
                        float a = 0.f;
                        #pragma unroll
                        for (int k = 0; k < 6; ++k) a = fmaf(R[i*6+k], R[k*6+c], a);
                        T[i*6+c] = a;
                    }
                }
                #pragma unroll
                for (int e = 0; e < 36; ++e) R[e] = T[e];
            }
            #pragma unroll
            for (int c = 0; c < 6; ++c) {
                const float cc = cosf(rphi * (float)c), ss = sinf(rphi * (float)c);
                #pragma unroll
                for (int o = 0; o < 6; ++o)
                    G[o*6 + c] = make_float2(R[o*6+c]*cc, R[o*6+c]*ss);
            }
        } else {
            // Dp[m] = diag(e^{i kap n^2}) @ disp(dr,dp) @ diag(e^{i rphi2 n})
            const int m = gi - 5;
            const float dr   = lin[l*63 + 53 + m];
            const float dp   = lin[l*63 + 58 + m];
            const float rphi = (m < 4) ? lin[l*63 + 49 + m] : 0.f;
            const float kap  = (l < 3) ? act[l*5 + m] : ((m < 2) ? lact[m] : 0.f);
            const float2 al = make_float2(dr * cosf(dp), dr * sinf(dp));
            float2 R[36], T[36];
            #pragma unroll
            for (int e = 0; e < 36; ++e)
                R[e] = make_float2((e % 7 == 0) ? 1.f : 0.f, 0.f);
            float2 cm[6], cpb[6];
            #pragma unroll
            for (int i = 0; i < 6; ++i) {
                const float sm  = sqrtf((float)i)     * 0.015625f;
                const float sp2 = sqrtf((float)(i+1)) * 0.015625f;
                cm[i]  = make_float2( al.x*sm,  al.y*sm);
                cpb[i] = make_float2(-al.x*sp2, al.y*sp2);
            }
            for (int k = 16; k >= 1; --k) {
                const float invk = 1.f / (float)k;
                #pragma unroll
                for (int i = 0; i < 6; ++i) {
                    #pragma unroll
                    for (int c = 0; c < 6; ++c) {
                        float ax = 0.f, ay = 0.f;
                        if (i >= 1) cmadd(ax, ay, cm[i],  R[(i-1)*6 + c]);
                        if (i < 5)  cmadd(ax, ay, cpb[i], R[(i+1)*6 + c]);
                        T[i*6+c] = make_float2(((i == c) ? 1.f : 0.f) + ax*invk, ay*invk);
                    }
                }
                #pragma unroll
                for (int e = 0; e < 36; ++e) R[e] = T[e];
            }
            for (int s2 = 0; s2 < 6; ++s2) {
                #pragma unroll
                for (int i = 0; i < 6; ++i) {
                    #pragma unroll
                    for (int c = 0; c < 6; ++c) {
                        float ax = 0.f, ay = 0.f;
                        #pragma unroll
                        for (int k = 0; k < 6; ++k) cmadd(ax, ay, R[i*6+k], R[k*6+c]);
                        T[i*6+c] = make_float2(ax, ay);
                    }
                }
                #pragma unroll
                for (int e = 0; e < 36; ++e) R[e] = T[e];
            }
            #pragma unroll
            for (int o = 0; o < 6; ++o) {
                const float ko = kap * (float)(o*o);
                const float2 kp = make_float2(cosf(ko), sinf(ko));
                #pragma unroll
                for (int c = 0; c < 6; ++c) {
                    const float rc = rphi * (float)c;
                    const float2 rp = make_float2(cosf(rc), sinf(rc));
                    const float2 z = R[o*6 + c];
                    const float2 t1 = make_float2(kp.x*z.x - kp.y*z.y, kp.x*z.y + kp.y*z.x);
                    G[o*6 + c] = make_float2(t1.x*rp.x - t1.y*rp.y, t1.x*rp.y + t1.y*rp.x);
                }
            }
        }
        h2* outp = sgh + (l*10 + gi)*72;
        #pragma unroll
        for (int e = 0; e < 36; ++e) {
            outp[2*e    ] = (h2){(_Float16)G[e].x, (_Float16)(-G[e].y)};
            outp[2*e + 1] = (h2){(_Float16)G[e].y, (_Float16)( G[e].x)};
        }
    }
}

// ---------------------------------------------------------------------------
// Initial displacement (phi=0 -> real expm): column 0 per (batch, mode).
// ---------------------------------------------------------------------------
__global__ void dcol_kernel(const float* __restrict__ x,
                            float* __restrict__ dcol, const int total)
{
    const int i = blockIdx.x * 256 + threadIdx.x;
    if (i >= total) return;
    const float xv = x[i];
    float a[5];
    #pragma unroll
    for (int j = 0; j < 5; ++j) a[j] = xv * sqrtf((float)(j+1)) * 0.015625f;
    float R[36], T[36];
    #pragma unroll
    for (int e = 0; e < 36; ++e) R[e] = (e % 7 == 0) ? 1.f : 0.f;
    for (int k = 16; k >= 1; --k) {
        const float invk = 1.f / (float)k;
        #pragma unroll
        for (int r = 0; r < 6; ++r) {
            #pragma unroll
            for (int c = 0; c < 6; ++c) {
                float acc = 0.f;
                if (r >= 1) acc = fmaf( a[r-1], R[(r-1)*6 + c], acc);
                if (r < 5)  acc = fmaf(-a[r],   R[(r+1)*6 + c], acc);
                T[r*6+c] = ((r == c) ? 1.f : 0.f) + acc*invk;
            }
        }
        #pragma unroll
        for (int e = 0; e < 36; ++e) R[e] = T[e];
    }
    for (int s2 = 0; s2 < 6; ++s2) {
        #pragma unroll
        for (int r = 0; r < 6; ++r) {
            #pragma unroll
            for (int c = 0; c < 6; ++c) {
                float acc = 0.f;
                #pragma unroll
                for (int k = 0; k < 6; ++k) acc = fmaf(R[r*6+k], R[k*6+c], acc);
                T[r*6+c] = acc;
            }
        }
        #pragma unroll
        for (int e = 0; e < 36; ++e) R[e] = T[e];
    }
    #pragma unroll
    for (int j = 0; j < 6; ++j) dcol[i*6 + j] = R[j*6 + 0];
}

// ---------------------------------------------------------------------------
// Main kernel building blocks (fp16x2 psi in LDS, dot2 MACs)
// ---------------------------------------------------------------------------

template<int K, int n>
struct BDBlock {
    static __device__ __forceinline__ void run(const h2* __restrict__ U,
                                               h2* __restrict__ psi,
                                               const int base, const bool act) {
        constexpr int SA = MS[K], SB = MS[K+1];
        constexpr int sn = BS_SN[n], uoff = BS_OFF[n];
        constexpr int imin = (n > 5) ? (n - 5) : 0;
        h2 vb[sn];
        #pragma unroll
        for (int q = 0; q < sn; ++q) {
            const int c = 5*(imin + q) + n;
            vb[q] = psi[base + (c/6)*SA + (c%6)*SB];
        }
        h2 ob[sn];
        #pragma unroll
        for (int p = 0; p < sn; ++p) {
            float re = 0.f, im = 0.f;
            #pragma unroll
            for (int q = 0; q < sn; ++q) {
                re = fdot2(U[2*(uoff + p*sn + q)    ], vb[q], re);
                im = fdot2(U[2*(uoff + p*sn + q) + 1], vb[q], im);
            }
            ob[p] = (h2){(_Float16)re, (_Float16)im};
        }
        if (act) {
            #pragma unroll
            for (int p = 0; p < sn; ++p) {
                const int c = 5*(imin + p) + n;
                psi[base + (c/6)*SA + (c%6)*SB] = ob[p];
            }
        }
        BDBlock<K, n+1>::run(U, psi, base, act);
    }
};
template<int K>
struct BDBlock<K, 11> {
    static __device__ __forceinline__ void run(const h2*, h2*, int, bool) {}
};

template<int K>
__device__ __forceinline__ void apply2_bd(const h2* __restrict__ U,
                                          h2* __restrict__ psi,
                                          const int base, const bool act)
{
    BDBlock<K, 0>::run(U, psi, base, act);
    __syncthreads();
}

template<int M5>
__device__ __forceinline__ void apply1_u(const h2* __restrict__ G,
                                         h2* __restrict__ psi, const int tid)
{
    constexpr int SM = MS[M5];
    h2 g[72];
    #pragma unroll
    for (int k = 0; k < 72; ++k) g[k] = G[k];   // block-uniform loads
    for (int it = 0; it < 6; ++it) {
        const int fr = tid + it*256;
        const bool act = fr < 1296;
        const int f  = act ? fr : 1295;
        const int d0 = f / 216, r0 = f - d0*216;
        const int d1 = r0 / 36, r1 = r0 - d1*36;
        const int d2 = r1 / 6,  d3 = r1 - d2*6;
        const int base = d0*SP1[M5][0] + d1*SP1[M5][1] + d2*SP1[M5][2] + d3*SP1[M5][3];
        h2 v6[6];
        #pragma unroll
        for (int j = 0; j < 6; ++j) v6[j] = psi[base + j*SM];
        h2 o6[6];
        #pragma unroll
        for (int o = 0; o < 6; ++o) {
            float re = 0.f, im = 0.f;
            #pragma unroll
            for (int j = 0; j < 6; ++j) {
                re = fdot2(g[2*(o*6 + j)    ], v6[j], re);
                im = fdot2(g[2*(o*6 + j) + 1], v6[j], im);
            }
            o6[o] = (h2){(_Float16)re, (_Float16)im};
        }
        if (act) {
            #pragma unroll
            for (int o = 0; o < 6; ++o) psi[base + o*SM] = o6[o];
        }
    }
    __syncthreads();
}

__global__ __launch_bounds__(256, 5)
void qnet_kernel(const h2* __restrict__ bs,
                 const h2* __restrict__ sg,
                 const float* __restrict__ dcol,
                 float* __restrict__ out)
{
    // strides {1365,227,37,6,1}: used offsets within each i0-superblock are
    // 0..1355, leaving gaps [s*1365+1356, s*1365+1364] (9 dwords each) that
    // the index formula can never produce -> scalar scratch lives there.
    __shared__ h2 psi[8190];    // 32760 B -> 5 blocks/CU
    const int tid = threadIdx.x;
    const int b   = blockIdx.x;

    // stf[m][j] in gap of superblock m (m=0..4); red in gap of superblock 5
    if (tid < 30) {
        const int m = tid / 6, j = tid - m*6;
        ((float*)(psi + m*1365 + 1356))[j] = dcol[b*30 + tid];
    }
    __syncthreads();
    {
        const float* g0 = (const float*)(psi + 0*1365 + 1356);
        const float* g1 = (const float*)(psi + 1*1365 + 1356);
        const float* g2 = (const float*)(psi + 2*1365 + 1356);
        const float* g3 = (const float*)(psi + 3*1365 + 1356);
        const float* g4 = (const float*)(psi + 4*1365 + 1356);
        for (int e = tid; e < 7776; e += 256) {
            int t = e;
            const int i4 = t % 6; t /= 6;
            const int i3 = t % 6; t /= 6;
            const int i2 = t % 6; t /= 6;
            const int i1 = t % 6; t /= 6;
            const int i0 = t;
            const int addr = i0*1365 + i1*227 + i2*37 + i3*6 + i4;
            const float val = g0[i0]*g1[i1]*g2[i2]*g3[i3]*g4[i4];
            psi[addr] = (h2){(_Float16)val, (_Float16)0.f};
        }
    }
    __syncthreads();

    // per-thread fiber bases for each K (fixed all kernel)
    const int f  = (tid < 216) ? tid : 215;
    const int d0 = f / 36, rem = f - d0*36;
    const int d1 = rem / 6, d2 = rem - d1*6;
    const bool act = tid < 216;
    int baseK[4];
    #pragma unroll
    for (int k = 0; k < 4; ++k)
        baseK[k] = d0*SP2[k][0] + d1*SP2[k][1] + d2*SP2[k][2];

    for (int l = 0; l < 4; ++l) {
        const h2* bsl = bs + l * 20 * 292;
        const h2* sgl = sg + l * 10 * 72;
        for (int half = 0; half < 2; ++half) {
            const h2* bh = bsl + half * 10 * 292;
            // rail order k = {0,2,1,3,0,2,1,3,0,2}
            apply2_bd<0>(bh + 0*292, psi, baseK[0], act);
            apply2_bd<2>(bh + 1*292, psi, baseK[2], act);
            apply2_bd<1>(bh + 2*292, psi, baseK[1], act);
            apply2_bd<3>(bh + 3*292, psi, baseK[3], act);
            apply2_bd<0>(bh + 4*292, psi, baseK[0], act);
            apply2_bd<2>(bh + 5*292, psi, baseK[2], act);
            apply2_bd<1>(bh + 6*292, psi, baseK[1], act);
            apply2_bd<3>(bh + 7*292, psi, baseK[3], act);
            apply2_bd<0>(bh + 8*292, psi, baseK[0], act);
            apply2_bd<2>(bh + 9*292, psi, baseK[2], act);
            const h2* sh = sgl + half * 5 * 72;
            apply1_u<0>(sh + 0*72, psi, tid);
            apply1_u<1>(sh + 1*72, psi, tid);
            apply1_u<2>(sh + 2*72, psi, tid);
            apply1_u<3>(sh + 3*72, psi, tid);
            apply1_u<4>(sh + 4*72, psi, tid);
        }
    }

    // <psi| X psi> on modes 0,1
    float s0 = 0.f, s1 = 0.f;
    for (int fr = tid; fr < 1296; fr += 256) {
        const int e0 = fr / 216, r0 = fr - e0*216;
        const int e1 = r0 / 36, r1 = r0 - e1*36;
        const int base0 = e0*227 + e1*37 + r1;      // spectators of mode 0
        #pragma unroll
        for (int j = 0; j < 5; ++j) {
            const vf2 p0 = h2f(psi[base0 + j*1365]);
            const vf2 p1 = h2f(psi[base0 + (j+1)*1365]);
            s0 = fmaf(sqrtf((float)(j+1)), fmaf(p0.y, p1.y, p0.x*p1.x), s0);
        }
        const int base1 = e0*1365 + e1*37 + r1;     // spectators of mode 1
        #pragma unroll
        for (int j = 0; j < 5; ++j) {
            const vf2 p0 = h2f(psi[base1 + j*227]);
            const vf2 p1 = h2f(psi[base1 + (j+1)*227]);
            s1 = fmaf(sqrtf((float)(j+1)), fmaf(p0.y, p1.y, p0.x*p1.x), s1);
        }
    }
    #pragma unroll
    for (int off = 32; off > 0; off >>= 1) {
        s0 += __shfl_down(s0, off, 64);
        s1 += __shfl_down(s1, off, 64);
    }
    float* red = (float*)(psi + 5*1365 + 1356);  // gap of superblock 5 (never aliased)
    if ((tid & 63) == 0) { red[(tid>>6)*2] = s0; red[(tid>>6)*2 + 1] = s1; }
    __syncthreads();
    if (tid == 0) {
        out[b*2 + 0] = 2.f*(red[0] + red[2] + red[4] + red[6]);
        out[b*2 + 1] = 2.f*(red[1] + red[3] + red[5] + red[7]);
    }
}

// ---------------------------------------------------------------------------
extern "C" void kernel_launch(void* const* d_in, const int* in_sizes, int n_in,
                              void* d_out, int out_size, void* d_ws, size_t ws_size,
                              hipStream_t stream)
{
    const float* x    = (const float*)d_in[0];   // (B, 5)
    const float* lin  = (const float*)d_in[1];   // (4, 63)
    const float* act  = (const float*)d_in[2];   // (3, 5)
    const float* lact = (const float*)d_in[3];   // (5,)
    float* out = (float*)d_out;                  // (B, 2) float32

    const int B = in_sizes[0] / 5;

    // ws layout: 80 BS gates (292 h2) | 40 single gates (72 h2) | dcol f32
    h2*    bsh = (h2*)d_ws;
    h2*    sgh = bsh + 80*292;
    float* dc  = (float*)(sgh + 40*72);

    gates_kernel<<<dim3(81), dim3(256), 0, stream>>>(lin, act, lact, bsh, sgh);
    const int total = B * 5;
    dcol_kernel<<<dim3((total + 255)/256), dim3(256), 0, stream>>>(x, dc, total);
    qnet_kernel<<<dim3(B), dim3(256), 0, stream>>>(bsh, sgh, dc, out);
}

// Round 6
// 972.917 us; speedup vs baseline: 1.6734x; 1.0801x over previous
//
#include <hip/hip_runtime.h>

// QuantumDenseNet R6: complex MAC as 2x v_pk_fma_f16 (h2 accumulate) with
// gates pre-packed {ur,ur},{-ui,ui}; operand swap folds into op_sel. Removes
// all store-side cvt/pack VALU (was ~27% of issue). psi fp16x2 in LDS,
// strides {1365,227,37,6,1}, 32760 B -> 5 blocks/CU ceiling. VGPR kept <=64
// (>64 would cap 4 waves/SIMD and lose a block).

typedef float    vf2 __attribute__((ext_vector_type(2)));
typedef _Float16 h2  __attribute__((ext_vector_type(2)));

__device__ __forceinline__ h2 pkfma(const h2 a, const h2 b, const h2 c) {
    return __builtin_elementwise_fma(a, b, c);
}
__device__ __forceinline__ h2 swp(const h2 v) {
    return __builtin_shufflevector(v, v, 1, 0);
}
__device__ __forceinline__ vf2 h2f(const h2 h) { return (vf2){(float)h.x, (float)h.y}; }

__device__ __forceinline__ void cmadd(float &ax, float &ay, const float2 u, const float2 v) {
    ax = fmaf(u.x, v.x, ax);
    ax = fmaf(-u.y, v.y, ax);
    ay = fmaf(u.x, v.y, ay);
    ay = fmaf(u.y, v.x, ay);
}

// block-diagonal structure of the 36x36 BS gate (total photon number n=0..10)
constexpr int BS_SN[11]  = {1,2,3,4,5,6,5,4,3,2,1};
constexpr int BS_OFF[11] = {0,1,5,14,30,55,91,116,132,141,145};
// mode strides (h2 = 4B units); mod 32 = {21,3,5,6,1}
constexpr int MS[5] = {1365, 227, 37, 6, 1};
// apply2 spectator strides (descending) for gate pair (K,K+1)
constexpr int SP2[4][3] = {
    {37, 6, 1},        // K=0: spectators 2,3,4
    {1365, 6, 1},      // K=1: spectators 0,3,4
    {1365, 227, 1},    // K=2: spectators 0,1,4
    {1365, 227, 37},   // K=3: spectators 0,1,2
};
// apply1 spectator strides (descending) for mode M
constexpr int SP1[5][4] = {
    {227, 37, 6, 1},
    {1365, 37, 6, 1},
    {1365, 227, 6, 1},
    {1365, 227, 37, 1},
    {1365, 227, 37, 6},
};

// runtime-indexed copy for gates_kernel packing
__device__ const int d_BS_OFF[12] = {0,1,5,14,30,55,91,116,132,141,145,146};
__device__ const int d_BS_SN[11]  = {1,2,3,4,5,6,5,4,3,2,1};

// ---------------------------------------------------------------------------
// Gate precompute: blocks 0..79 -> BS gates (fp32 expm in LDS, packed
// block-diag as h2 pk-fma pairs {ur,ur},{-ui,ui}: 292 h2/gate),
// block 80 -> 40 single-mode combined gates (72 h2/gate).
// ---------------------------------------------------------------------------
__global__ void gates_kernel(const float* __restrict__ lin,
                             const float* __restrict__ act,
                             const float* __restrict__ lact,
                             h2* __restrict__ bsh,
                             h2* __restrict__ sgh)
{
    __shared__ float2 B0[1296];
    __shared__ float2 B1[1296];
    const int tid = threadIdx.x;

    if (blockIdx.x < 80) {
        const int g = blockIdx.x;
        const int l = g / 20;
        const int w = g % 20;
        const int q = w / 10;
        const int n = w % 10;
        const float theta = lin[l*63 + (q ? 29 : 0) + n];
        const float phi   = lin[l*63 + (q ? 39 : 10) + n];
        const float ts = theta * 0.015625f;
        const float cp = cosf(phi), sp = sinf(phi);
        const float2 u  = make_float2( ts*cp, ts*sp);
        const float2 w2 = make_float2(-ts*cp, ts*sp);

        float2 *R = B0, *T = B1;
        for (int e = tid; e < 1296; e += 256)
            R[e] = make_float2((e % 37 == 0) ? 1.f : 0.f, 0.f);
        __syncthreads();

        for (int k = 16; k >= 1; --k) {
            const float invk = 1.f / (float)k;
            for (int e = tid; e < 1296; e += 256) {
                const int row = e / 36, c = e - row*36;
                const int i = row / 6, j = row - (row/6)*6;
                float ax = 0.f, ay = 0.f;
                if (i < 5 && j > 0) {
                    const float coef = sqrtf((float)((i+1)*j));
                    const float2 x = R[(row+5)*36 + c];
                    const float px = u.x*x.x - u.y*x.y;
                    const float py = u.x*x.y + u.y*x.x;
                    ax = fmaf(coef, px, ax); ay = fmaf(coef, py, ay);
                }
                if (i > 0 && j < 5) {
                    const float coef = sqrtf((float)(i*(j+1)));
                    const float2 x = R[(row-5)*36 + c];
                    const float px = w2.x*x.x - w2.y*x.y;
                    const float py = w2.x*x.y + w2.y*x.x;
                    ax = fmaf(coef, px, ax); ay = fmaf(coef, py, ay);
                }
                T[e] = make_float2(((row == c) ? 1.f : 0.f) + ax*invk, ay*invk);
            }
            __syncthreads();
            float2* tmp = R; R = T; T = tmp;
        }
        for (int s2 = 0; s2 < 6; ++s2) {
            for (int e = tid; e < 1296; e += 256) {
                const int row = e / 36, c = e - row*36;
                float ax = 0.f, ay = 0.f;
                #pragma unroll 6
                for (int k = 0; k < 36; ++k)
                    cmadd(ax, ay, R[row*36 + k], R[k*36 + c]);
                T[e] = make_float2(ax, ay);
            }
            __syncthreads();
            float2* tmp = R; R = T; T = tmp;
        }
        for (int idx = tid; idx < 146; idx += 256) {
            int nn = 0;
            while (idx >= d_BS_OFF[nn+1]) ++nn;
            const int sn  = d_BS_SN[nn];
            const int rel = idx - d_BS_OFF[nn];
            const int p = rel / sn, qq = rel % sn;
            const int imin = (nn > 5) ? (nn - 5) : 0;
            const int row = 5*(imin + p)  + nn;
            const int col = 5*(imin + qq) + nn;
            const float2 z = R[row*36 + col];
            bsh[g*292 + 2*idx    ] = (h2){(_Float16)z.x,  (_Float16)z.x};
            bsh[g*292 + 2*idx + 1] = (h2){(_Float16)(-z.y), (_Float16)z.y};
        }
    } else {
        const int t = tid;
        if (t >= 40) return;
        const int l  = t / 10;
        const int gi = t % 10;
        float2 G[36];
        if (gi < 5) {
            // Sq[m] = squeeze(r) @ diag(e^{i rphi1 * n})
            const int m = gi;
            const float r    = lin[l*63 + 24 + m];
            const float rphi = (m < 4) ? lin[l*63 + 20 + m] : 0.f;
            float R[36], T[36];
            #pragma unroll
            for (int e = 0; e < 36; ++e) R[e] = (e % 7 == 0) ? 1.f : 0.f;
            float hp[4];
            #pragma unroll
            for (int i = 0; i < 4; ++i)
                hp[i] = 0.5f * r * sqrtf((float)((i+1)*(i+2))) * 0.015625f;
            for (int k = 16; k >= 1; --k) {
                const float invk = 1.f / (float)k;
                #pragma unroll
                for (int i = 0; i < 6; ++i) {
                    #pragma unroll
                    for (int c = 0; c < 6; ++c) {
                        float a = 0.f;
                        if (i < 4)  a = fmaf( hp[i],   R[(i+2)*6 + c], a);
                        if (i >= 2) a = fmaf(-hp[i-2], R[(i-2)*6 + c], a);
                        T[i*6+c] = ((i == c) ? 1.f : 0.f) + a*invk;
                    }
                }
                #pragma unroll
                for (int e = 0; e < 36; ++e) R[e] = T[e];
            }
            for (int s2 = 0; s2 < 6; ++s2) {
                #pragma unroll
                for (int i = 0; i < 6; ++i) {
                    #pragma unroll
                    for (int c = 0; c < 6; ++c) {
                        float a = 0.f;
                        #pragma unroll
                        for (int k = 0; k < 6; ++k) a = fmaf(R[i*6+k], R[k*6+c], a);
                        T[i*6+c] = a;
                    }
                }
                #pragma unroll
                for (int e = 0; e < 36; ++e) R[e] = T[e];
            }
            #pragma unroll
            for (int c = 0; c < 6; ++c) {
                const float cc = cosf(rphi * (float)c), ss = sinf(rphi * (float)c);
                #pragma unroll
                for (int o = 0; o < 6; ++o)
                    G[o*6 + c] = make_float2(R[o*6+c]*cc, R[o*6+c]*ss);
            }
        } else {
            // Dp[m] = diag(e^{i kap n^2}) @ disp(dr,dp) @ diag(e^{i rphi2 n})
            const int m = gi - 5;
            const float dr   = lin[l*63 + 53 + m];
            const float dp   = lin[l*63 + 58 + m];
            const float rphi = (m < 4) ? lin[l*63 + 49 + m] : 0.f;
            const float kap  = (l < 3) ? act[l*5 + m] : ((m < 2) ? lact[m] : 0.f);
            const float2 al = make_float2(dr * cosf(dp), dr * sinf(dp));
            float2 R[36], T[36];
            #pragma unroll
            for (int e = 0; e < 36; ++e)
                R[e] = make_float2((e % 7 == 0) ? 1.f : 0.f, 0.f);
            float2 cm[6], cpb[6];
            #pragma unroll
            for (int i = 0; i < 6; ++i) {
                const float sm  = sqrtf((float)i)     * 0.015625f;
                const float sp2 = sqrtf((float)(i+1)) * 0.015625f;
                cm[i]  = make_float2( al.x*sm,  al.y*sm);
                cpb[i] = make_float2(-al.x*sp2, al.y*sp2);
            }
            for (int k = 16; k >= 1; --k) {
                const float invk = 1.f / (float)k;
                #pragma unroll
                for (int i = 0; i < 6; ++i) {
                    #pragma unroll
                    for (int c = 0; c < 6; ++c) {
                        float ax = 0.f, ay = 0.f;
                        if (i >= 1) cmadd(ax, ay, cm[i],  R[(i-1)*6 + c]);
                        if (i < 5)  cmadd(ax, ay, cpb[i], R[(i+1)*6 + c]);
                        T[i*6+c] = make_float2(((i == c) ? 1.f : 0.f) + ax*invk, ay*invk);
                    }
                }
                #pragma unroll
                for (int e = 0; e < 36; ++e) R[e] = T[e];
            }
            for (int s2 = 0; s2 < 6; ++s2) {
                #pragma unroll
                for (int i = 0; i < 6; ++i) {
                    #pragma unroll
                    for (int c = 0; c < 6; ++c) {
                        float ax = 0.f, ay = 0.f;
                        #pragma unroll
                        for (int k = 0; k < 6; ++k) cmadd(ax, ay, R[i*6+k], R[k*6+c]);
                        T[i*6+c] = make_float2(ax, ay);
                    }
                }
                #pragma unroll
                for (int e = 0; e < 36; ++e) R[e] = T[e];
            }
            #pragma unroll
            for (int o = 0; o < 6; ++o) {
                const float ko = kap * (float)(o*o);
                const float2 kp = make_float2(cosf(ko), sinf(ko));
                #pragma unroll
                for (int c = 0; c < 6; ++c) {
                    const float rc = rphi * (float)c;
                    const float2 rp = make_float2(cosf(rc), sinf(rc));
                    const float2 z = R[o*6 + c];
                    const float2 t1 = make_float2(kp.x*z.x - kp.y*z.y, kp.x*z.y + kp.y*z.x);
                    G[o*6 + c] = make_float2(t1.x*rp.x - t1.y*rp.y, t1.x*rp.y + t1.y*rp.x);
                }
            }
        }
        h2* outp = sgh + (l*10 + gi)*72;
        #pragma unroll
        for (int e = 0; e < 36; ++e) {
            outp[2*e    ] = (h2){(_Float16)G[e].x,  (_Float16)G[e].x};
            outp[2*e + 1] = (h2){(_Float16)(-G[e].y), (_Float16)G[e].y};
        }
    }
}

// ---------------------------------------------------------------------------
// Initial displacement (phi=0 -> real expm): column 0 per (batch, mode).
// ---------------------------------------------------------------------------
__global__ void dcol_kernel(const float* __restrict__ x,
                            float* __restrict__ dcol, const int total)
{
    const int i = blockIdx.x * 256 + threadIdx.x;
    if (i >= total) return;
    const float xv = x[i];
    float a[5];
    #pragma unroll
    for (int j = 0; j < 5; ++j) a[j] = xv * sqrtf((float)(j+1)) * 0.015625f;
    float R[36], T[36];
    #pragma unroll
    for (int e = 0; e < 36; ++e) R[e] = (e % 7 == 0) ? 1.f : 0.f;
    for (int k = 16; k >= 1; --k) {
        const float invk = 1.f / (float)k;
        #pragma unroll
        for (int r = 0; r < 6; ++r) {
            #pragma unroll
            for (int c = 0; c < 6; ++c) {
                float acc = 0.f;
                if (r >= 1) acc = fmaf( a[r-1], R[(r-1)*6 + c], acc);
                if (r < 5)  acc = fmaf(-a[r],   R[(r+1)*6 + c], acc);
                T[r*6+c] = ((r == c) ? 1.f : 0.f) + acc*invk;
            }
        }
        #pragma unroll
        for (int e = 0; e < 36; ++e) R[e] = T[e];
    }
    for (int s2 = 0; s2 < 6; ++s2) {
        #pragma unroll
        for (int r = 0; r < 6; ++r) {
            #pragma unroll
            for (int c = 0; c < 6; ++c) {
                float acc = 0.f;
                #pragma unroll
                for (int k = 0; k < 6; ++k) acc = fmaf(R[r*6+k], R[k*6+c], acc);
                T[r*6+c] = acc;
            }
        }
        #pragma unroll
        for (int e = 0; e < 36; ++e) R[e] = T[e];
    }
    #pragma unroll
    for (int j = 0; j < 6; ++j) dcol[i*6 + j] = R[j*6 + 0];
}

// ---------------------------------------------------------------------------
// Main kernel building blocks (fp16x2 psi in LDS, pk_fma_f16 MACs)
// ---------------------------------------------------------------------------

template<int K, int n>
struct BDBlock {
    static __device__ __forceinline__ void run(const h2* __restrict__ U,
                                               h2* __restrict__ psi,
                                               const int base, const bool act) {
        constexpr int SA = MS[K], SB = MS[K+1];
        constexpr int sn = BS_SN[n], uoff = BS_OFF[n];
        constexpr int imin = (n > 5) ? (n - 5) : 0;
        h2 vb[sn];
        #pragma unroll
        for (int q = 0; q < sn; ++q) {
            const int c = 5*(imin + q) + n;
            vb[q] = psi[base + (c/6)*SA + (c%6)*SB];
        }
        h2 ob[sn];
        #pragma unroll
        for (int p = 0; p < sn; ++p) {
            h2 acc = (h2){(_Float16)0.f, (_Float16)0.f};
            #pragma unroll
            for (int q = 0; q < sn; ++q) {
                acc = pkfma(U[2*(uoff + p*sn + q)    ], vb[q],      acc);
                acc = pkfma(U[2*(uoff + p*sn + q) + 1], swp(vb[q]), acc);
            }
            ob[p] = acc;
        }
        if (act) {
            #pragma unroll
            for (int p = 0; p < sn; ++p) {
                const int c = 5*(imin + p) + n;
                psi[base + (c/6)*SA + (c%6)*SB] = ob[p];
            }
        }
        BDBlock<K, n+1>::run(U, psi, base, act);
    }
};
template<int K>
struct BDBlock<K, 11> {
    static __device__ __forceinline__ void run(const h2*, h2*, int, bool) {}
};

template<int K>
__device__ __forceinline__ void apply2_bd(const h2* __restrict__ U,
                                          h2* __restrict__ psi,
                                          const int base, const bool act)
{
    BDBlock<K, 0>::run(U, psi, base, act);
    __syncthreads();
}

template<int M5>
__device__ __forceinline__ void apply1_u(const h2* __restrict__ G,
                                         h2* __restrict__ psi, const int tid)
{
    constexpr int SM = MS[M5];
    h2 g[72];
    #pragma unroll
    for (int k = 0; k < 72; ++k) g[k] = G[k];   // block-uniform loads
    for (int it = 0; it < 6; ++it) {
        const int fr = tid + it*256;
        const bool act = fr < 1296;
        const int f  = act ? fr : 1295;
        const int d0 = f / 216, r0 = f - d0*216;
        const int d1 = r0 / 36, r1 = r0 - d1*36;
        const int d2 = r1 / 6,  d3 = r1 - d2*6;
        const int base = d0*SP1[M5][0] + d1*SP1[M5][1] + d2*SP1[M5][2] + d3*SP1[M5][3];
        h2 v6[6];
        #pragma unroll
        for (int j = 0; j < 6; ++j) v6[j] = psi[base + j*SM];
        h2 o6[6];
        #pragma unroll
        for (int o = 0; o < 6; ++o) {
            h2 acc = (h2){(_Float16)0.f, (_Float16)0.f};
            #pragma unroll
            for (int j = 0; j < 6; ++j) {
                acc = pkfma(g[2*(o*6 + j)    ], v6[j],      acc);
                acc = pkfma(g[2*(o*6 + j) + 1], swp(v6[j]), acc);
            }
            o6[o] = acc;
        }
        if (act) {
            #pragma unroll
            for (int o = 0; o < 6; ++o) psi[base + o*SM] = o6[o];
        }
    }
    __syncthreads();
}

__global__ __launch_bounds__(256, 5)
void qnet_kernel(const h2* __restrict__ bs,
                 const h2* __restrict__ sg,
                 const float* __restrict__ dcol,
                 float* __restrict__ out)
{
    // strides {1365,227,37,6,1}: used offsets within each i0-superblock are
    // 0..1355, leaving gaps [s*1365+1356, s*1365+1364] (9 dwords each) that
    // the index formula can never produce -> scalar scratch lives there.
    __shared__ h2 psi[8190];    // 32760 B -> 5 blocks/CU ceiling
    const int tid = threadIdx.x;
    const int b   = blockIdx.x;

    // stf[m][j] in gap of superblock m (m=0..4); red in gap of superblock 5
    if (tid < 30) {
        const int m = tid / 6, j = tid - m*6;
        ((float*)(psi + m*1365 + 1356))[j] = dcol[b*30 + tid];
    }
    __syncthreads();
    {
        const float* g0 = (const float*)(psi + 0*1365 + 1356);
        const float* g1 = (const float*)(psi + 1*1365 + 1356);
        const float* g2 = (const float*)(psi + 2*1365 + 1356);
        const float* g3 = (const float*)(psi + 3*1365 + 1356);
        const float* g4 = (const float*)(psi + 4*1365 + 1356);
        for (int e = tid; e < 7776; e += 256) {
            int t = e;
            const int i4 = t % 6; t /= 6;
            const int i3 = t % 6; t /= 6;
            const int i2 = t % 6; t /= 6;
            const int i1 = t % 6; t /= 6;
            const int i0 = t;
            const int addr = i0*1365 + i1*227 + i2*37 + i3*6 + i4;
            const float val = g0[i0]*g1[i1]*g2[i2]*g3[i3]*g4[i4];
            psi[addr] = (h2){(_Float16)val, (_Float16)0.f};
        }
    }
    __syncthreads();

    // per-thread fiber bases for each K (fixed all kernel)
    const int f  = (tid < 216) ? tid : 215;
    const int d0 = f / 36, rem = f - d0*36;
    const int d1 = rem / 6, d2 = rem - d1*6;
    const bool act = tid < 216;
    int baseK[4];
    #pragma unroll
    for (int k = 0; k < 4; ++k)
        baseK[k] = d0*SP2[k][0] + d1*SP2[k][1] + d2*SP2[k][2];

    for (int l = 0; l < 4; ++l) {
        const h2* bsl = bs + l * 20 * 292;
        const h2* sgl = sg + l * 10 * 72;
        for (int half = 0; half < 2; ++half) {
            const h2* bh = bsl + half * 10 * 292;
            // rail order k = {0,2,1,3,0,2,1,3,0,2}
            apply2_bd<0>(bh + 0*292, psi, baseK[0], act);
            apply2_bd<2>(bh + 1*292, psi, baseK[2], act);
            apply2_bd<1>(bh + 2*292, psi, baseK[1], act);
            apply2_bd<3>(bh + 3*292, psi, baseK[3], act);
            apply2_bd<0>(bh + 4*292, psi, baseK[0], act);
            apply2_bd<2>(bh + 5*292, psi, baseK[2], act);
            apply2_bd<1>(bh + 6*292, psi, baseK[1], act);
            apply2_bd<3>(bh + 7*292, psi, baseK[3], act);
            apply2_bd<0>(bh + 8*292, psi, baseK[0], act);
            apply2_bd<2>(bh + 9*292, psi, baseK[2], act);
            const h2* sh = sgl + half * 5 * 72;
            apply1_u<0>(sh + 0*72, psi, tid);
            apply1_u<1>(sh + 1*72, psi, tid);
            apply1_u<2>(sh + 2*72, psi, tid);
            apply1_u<3>(sh + 3*72, psi, tid);
            apply1_u<4>(sh + 4*72, psi, tid);
        }
    }

    // <psi| X psi> on modes 0,1
    float s0 = 0.f, s1 = 0.f;
    for (int fr = tid; fr < 1296; fr += 256) {
        const int e0 = fr / 216, r0 = fr - e0*216;
        const int e1 = r0 / 36, r1 = r0 - e1*36;
        const int base0 = e0*227 + e1*37 + r1;      // spectators of mode 0
        #pragma unroll
        for (int j = 0; j < 5; ++j) {
            const vf2 p0 = h2f(psi[base0 + j*1365]);
            const vf2 p1 = h2f(psi[base0 + (j+1)*1365]);
            s0 = fmaf(sqrtf((float)(j+1)), fmaf(p0.y, p1.y, p0.x*p1.x), s0);
        }
        const int base1 = e0*1365 + e1*37 + r1;     // spectators of mode 1
        #pragma unroll
        for (int j = 0; j < 5; ++j) {
            const vf2 p0 = h2f(psi[base1 + j*227]);
            const vf2 p1 = h2f(psi[base1 + (j+1)*227]);
            s1 = fmaf(sqrtf((float)(j+1)), fmaf(p0.y, p1.y, p0.x*p1.x), s1);
        }
    }
    #pragma unroll
    for (int off = 32; off > 0; off >>= 1) {
        s0 += __shfl_down(s0, off, 64);
        s1 += __shfl_down(s1, off, 64);
    }
    float* red = (float*)(psi + 5*1365 + 1356);  // gap of superblock 5 (never aliased)
    if ((tid & 63) == 0) { red[(tid>>6)*2] = s0; red[(tid>>6)*2 + 1] = s1; }
    __syncthreads();
    if (tid == 0) {
        out[b*2 + 0] = 2.f*(red[0] + red[2] + red[4] + red[6]);
        out[b*2 + 1] = 2.f*(red[1] + red[3] + red[5] + red[7]);
    }
}

// ---------------------------------------------------------------------------
extern "C" void kernel_launch(void* const* d_in, const int* in_sizes, int n_in,
                              void* d_out, int out_size, void* d_ws, size_t ws_size,
                              hipStream_t stream)
{
    const float* x    = (const float*)d_in[0];   // (B, 5)
    const float* lin  = (const float*)d_in[1];   // (4, 63)
    const float* act  = (const float*)d_in[2];   // (3, 5)
    const float* lact = (const float*)d_in[3];   // (5,)
    float* out = (float*)d_out;                  // (B, 2) float32

    const int B = in_sizes[0] / 5;

    // ws layout: 80 BS gates (292 h2) | 40 single gates (72 h2) | dcol f32
    h2*    bsh = (h2*)d_ws;
    h2*    sgh = bsh + 80*292;
    float* dc  = (float*)(sgh + 40*72);

    gates_kernel<<<dim3(81), dim3(256), 0, stream>>>(lin, act, lact, bsh, sgh);
    const int total = B * 5;
    dcol_kernel<<<dim3((total + 255)/256), dim3(256), 0, stream>>>(x, dc, total);
    qnet_kernel<<<dim3(B), dim3(256), 0, stream>>>(bsh, sgh, dc, out);
}